// Round 1
// baseline (166.195 us; speedup 1.0000x reference)
//
#include <hip/hip_runtime.h>
#include <hip/hip_bf16.h>
#include <math.h>

// Problem constants (fixed by the reference):
//   X: [16, 2048, 128] f32, Y: [16, 2048, 128] f32 -> out: [16, 2048, 2048] f32
#define Bb   16
#define Nn   2048
#define Mm   2048
#define Dd   128
#define TILE 128

typedef __attribute__((ext_vector_type(4))) float          f32x4;
typedef __attribute__((ext_vector_type(8))) unsigned short u16x8;
typedef __attribute__((ext_vector_type(8))) __bf16         bf16x8;

__device__ __forceinline__ unsigned short f32_to_bf16_rne(float f) {
  unsigned int u = __builtin_bit_cast(unsigned int, f);
  u += 0x7fffu + ((u >> 16) & 1u);   // round-to-nearest-even
  return (unsigned short)(u >> 16);
}

// One block computes a 128x128 output tile for one batch.
// 4 waves, each owning a 64x64 quadrant via 4x4 grid of 16x16x32 bf16 MFMAs.
__global__ __launch_bounds__(256)
void dist_sim_kernel(const float* __restrict__ X, const float* __restrict__ Y,
                     float* __restrict__ out) {
  // bf16 tiles, XOR-swizzled to kill the stride-256B bank conflict on b128 reads.
  __shared__ alignas(16) unsigned short Xs[TILE * Dd];
  __shared__ alignas(16) unsigned short Ys[TILE * Dd];
  __shared__ float xsq[TILE];
  __shared__ float ysq[TILE];

  const int tid = threadIdx.x;
  const int bm  = blockIdx.x;   // tile along M (Y rows / out cols)
  const int bn  = blockIdx.y;   // tile along N (X rows / out rows)
  const int b   = blockIdx.z;   // batch

  const float* Xb = X + ((size_t)b * Nn + (size_t)bn * TILE) * Dd;
  const float* Yb = Y + ((size_t)b * Mm + (size_t)bm * TILE) * Dd;

  // ---------------- stage: global f32 -> LDS bf16 (+ f32 row norms) ----------
  // Per iter: 256 threads cover 16 rows x 128 cols; thread t -> row sub=t>>4,
  // 8 contiguous floats at col (t&15)*8. Fully coalesced 32B/lane.
  const int sub = tid >> 4;
  const int c0  = (tid & 15) * 8;

  #pragma unroll
  for (int it = 0; it < 8; ++it) {
    const int row = it * 16 + sub;
    {
      const float* p = Xb + row * Dd + c0;
      f32x4 v0 = *(const f32x4*)(p);
      f32x4 v1 = *(const f32x4*)(p + 4);
      u16x8 w;
      float ss = 0.f;
      #pragma unroll
      for (int e = 0; e < 4; ++e) {
        ss += v0[e] * v0[e] + v1[e] * v1[e];
        w[e]     = f32_to_bf16_rne(v0[e]);
        w[e + 4] = f32_to_bf16_rne(v1[e]);
      }
      // 16 lanes share a row (lanes are wave-aligned: groups of 16 within 64)
      ss += __shfl_xor(ss, 1);
      ss += __shfl_xor(ss, 2);
      ss += __shfl_xor(ss, 4);
      ss += __shfl_xor(ss, 8);
      const int idx = (row * Dd + c0) ^ ((row & 7) << 3);  // swizzle (shorts)
      *(u16x8*)&Xs[idx] = w;
      if ((tid & 15) == 0) xsq[row] = ss;
    }
    {
      const float* p = Yb + row * Dd + c0;
      f32x4 v0 = *(const f32x4*)(p);
      f32x4 v1 = *(const f32x4*)(p + 4);
      u16x8 w;
      float ss = 0.f;
      #pragma unroll
      for (int e = 0; e < 4; ++e) {
        ss += v0[e] * v0[e] + v1[e] * v1[e];
        w[e]     = f32_to_bf16_rne(v0[e]);
        w[e + 4] = f32_to_bf16_rne(v1[e]);
      }
      ss += __shfl_xor(ss, 1);
      ss += __shfl_xor(ss, 2);
      ss += __shfl_xor(ss, 4);
      ss += __shfl_xor(ss, 8);
      const int idx = (row * Dd + c0) ^ ((row & 7) << 3);
      *(u16x8*)&Ys[idx] = w;
      if ((tid & 15) == 0) ysq[row] = ss;
    }
  }
  __syncthreads();

  // ---------------- MFMA: dot[n][m] over K=128 ------------------------------
  const int lane = tid & 63;
  const int wid  = tid >> 6;           // 0..3
  const int wr   = (wid >> 1) * 64;    // wave's row offset in tile
  const int wc   = (wid & 1) * 64;     // wave's col offset in tile
  const int fr   = lane & 15;          // fragment row/col within 16
  const int kg   = lane >> 4;          // k-group 0..3 (8 contiguous k each)

  f32x4 acc[4][4];
  #pragma unroll
  for (int i = 0; i < 4; ++i)
    #pragma unroll
    for (int j = 0; j < 4; ++j)
      acc[i][j] = (f32x4){0.f, 0.f, 0.f, 0.f};

  #pragma unroll
  for (int kk = 0; kk < 4; ++kk) {
    const int k0 = kk * 32 + kg * 8;
    bf16x8 a[4], bf[4];
    #pragma unroll
    for (int i = 0; i < 4; ++i) {
      const int row = wr + i * 16 + fr;
      const int idx = (row * Dd + k0) ^ ((row & 7) << 3);
      a[i] = __builtin_bit_cast(bf16x8, *(const u16x8*)&Xs[idx]);
    }
    #pragma unroll
    for (int j = 0; j < 4; ++j) {
      const int row = wc + j * 16 + fr;
      const int idx = (row * Dd + k0) ^ ((row & 7) << 3);
      bf[j] = __builtin_bit_cast(bf16x8, *(const u16x8*)&Ys[idx]);
    }
    #pragma unroll
    for (int i = 0; i < 4; ++i)
      #pragma unroll
      for (int j = 0; j < 4; ++j)
        acc[i][j] = __builtin_amdgcn_mfma_f32_16x16x32_bf16(a[i], bf[j], acc[i][j], 0, 0, 0);
  }

  // ---------------- epilogue: d2 -> 1/(1+sqrt(d2)) --------------------------
  // C/D layout (m89-verified): col = lane&15, row = (lane>>4)*4 + reg.
  float* outb = out + (size_t)b * Nn * Mm;
  #pragma unroll
  for (int i = 0; i < 4; ++i) {
    #pragma unroll
    for (int j = 0; j < 4; ++j) {
      const int col_l = wc + j * 16 + fr;
      const float yv  = ysq[col_l];
      const int  gcol = bm * TILE + col_l;
      #pragma unroll
      for (int r = 0; r < 4; ++r) {
        const int row_l = wr + i * 16 + kg * 4 + r;
        float d2 = xsq[row_l] + yv - 2.0f * acc[i][j][r];
        d2 = fmaxf(d2, 1e-7f);
        const float o = 1.0f / (1.0f + sqrtf(d2));
        outb[(size_t)(bn * TILE + row_l) * Mm + gcol] = o;
      }
    }
  }
}

extern "C" void kernel_launch(void* const* d_in, const int* in_sizes, int n_in,
                              void* d_out, int out_size, void* d_ws, size_t ws_size,
                              hipStream_t stream) {
  const float* X = (const float*)d_in[0];
  const float* Y = (const float*)d_in[1];
  float* out = (float*)d_out;
  dim3 grid(Mm / TILE, Nn / TILE, Bb);   // (16, 16, 16) = 4096 blocks
  dist_sim_kernel<<<grid, dim3(256, 1, 1), 0, stream>>>(X, Y, out);
}